// Round 1
// 980.220 us; speedup vs baseline: 1.0673x; 1.0673x over previous
//
#include <hip/hip_runtime.h>
#include <hip/hip_bf16.h>
#include <stdint.h>

// ElementalLinear: out[n,m,:] = x[n,m,:] @ W[species(n), l(m)] * 1/sqrt(128)
// n < 50000, m < 16 (l = 0,1,1,1,2x5,3x7), C_in = C_out = 128, 10 species.
// Strategy: bucket atoms by species (wave-aggregated atomics), then a
// BARRIER-FREE MFMA kernel: all x prefetched to bf16 registers up front
// (HBM latency fully overlapped), W read directly from L2 (bf16, scale
// pre-folded), exact 3125-block grid over the flat sorted atom list with a
// wave-uniform multi-pass loop for the <=9 bucket-boundary tiles.
// HBM floor ~820 MB -> ~130 us for k_main.

#define NATOMS 50000
#define NELEM  10
#define SHD    16
#define CC     128
#define APB    16
#define NTILES (NATOMS / APB)     // 3125, exact (50000 = 3125*16)

typedef __attribute__((ext_vector_type(8))) short bf16x8;   // 8 bf16 = 4 VGPR
typedef __attribute__((ext_vector_type(4))) float f32x4;

__device__ __forceinline__ unsigned short f2bf(float f) {
    union { float f; uint32_t u; } v; v.f = f;
    return (unsigned short)((v.u + 0x7FFFu + ((v.u >> 16) & 1u)) >> 16);
}

__device__ __forceinline__ int l_of_m(int m) {
    return (m == 0) ? 0 : (m < 4) ? 1 : (m < 9) ? 2 : 3;
}

// ---- pass 1a: species per atom + wave-aggregated bucket counts ----
__global__ void k_count(const float* __restrict__ y,
                        int* __restrict__ counts, int* __restrict__ species) {
    int n    = blockIdx.x * 256 + threadIdx.x;
    int lane = threadIdx.x & 63;
    int s = -1;
    if (n < NATOMS) {
        s = 0;
        #pragma unroll
        for (int j = 0; j < NELEM; ++j)
            if (y[(size_t)n * NELEM + j] > 0.5f) s = j;
        species[n] = s;
    }
    #pragma unroll
    for (int e = 0; e < NELEM; ++e) {
        unsigned long long m = __ballot(s == e);
        if (m != 0ull && lane == (__ffsll(m) - 1))
            atomicAdd(&counts[e], __popcll(m));
    }
}

// ---- pass 1b: prefix-sum offsets (10 entries) ----
__global__ void k_offsets(const int* __restrict__ counts, int* __restrict__ offsets) {
    if (blockIdx.x == 0 && threadIdx.x == 0) {
        int acc = 0;
        for (int e2 = 0; e2 < NELEM; ++e2) { offsets[e2] = acc; acc += counts[e2]; }
    }
}

// ---- pass 1c: scatter (atom id << 4 | species) into sorted list ----
__global__ void k_scatter(const int* __restrict__ species, const int* __restrict__ offsets,
                          int* __restrict__ cursors, int* __restrict__ idxb) {
    int n    = blockIdx.x * 256 + threadIdx.x;
    int lane = threadIdx.x & 63;
    int s = (n < NATOMS) ? species[n] : -1;
    #pragma unroll
    for (int e = 0; e < NELEM; ++e) {
        unsigned long long m = __ballot(s == e);
        if (m == 0ull) continue;                  // wave-uniform
        int leader = __ffsll(m) - 1;
        int bp = 0;
        if (lane == leader) bp = atomicAdd(&cursors[e], __popcll(m));
        bp = __shfl(bp, leader, 64);
        if (s == e) {
            int pos = __popcll(m & ((1ull << lane) - 1ull));
            idxb[offsets[e] + bp + pos] = (n << 4) | s;
        }
    }
}

// ---- pass 1d: W fp32 [e,l,k,c] -> bf16 transposed Wt[e,l,c,k], scale folded ----
__global__ void k_twt(const float* __restrict__ w, unsigned short* __restrict__ wt) {
    int i = blockIdx.x * 256 + threadIdx.x;
    if (i >= NELEM * 4 * CC * CC) return;
    int c  = i & 127;
    int k  = (i >> 7) & 127;
    int el = i >> 14;                     // e*4 + l
    wt[((size_t)el * CC + c) * CC + k] = f2bf(w[i] * 0.08838834764831845f);
}

// ---- main: barrier-free MFMA over 16-atom tiles of the sorted list ----
// 4 waves; wave w owns m in [4w,4w+4) x 128 cols. A rows = 16 atoms.
// All x prefetched as bf16 (axr, 64 VGPR); B frags loaded straight from L2.
__global__ __launch_bounds__(256, 2)
void k_main(const float* __restrict__ x,
            const unsigned short* __restrict__ wt,
            const int* __restrict__ idxb,
            float* __restrict__ out) {
    int t    = blockIdx.x;
    int base = t * APB;
    int tid  = threadIdx.x;
    int lane = tid & 63;
    int wv   = tid >> 6;
    int quad = lane >> 4;
    int l16  = lane & 15;

    int pk   = idxb[base + l16];
    int aid  = pk >> 4;
    int mysp = pk & 15;
    const float* xa = x + (size_t)aid * (SHD * CC);

    // prefetch + convert all x fragments this wave needs: axr[mi][kt]
    bf16x8 axr[4][4];
    #pragma unroll
    for (int mi = 0; mi < 4; ++mi) {
        const float* xp = xa + (wv * 4 + mi) * CC + quad * 8;
        float4 v0[4], v1[4];
        #pragma unroll
        for (int kt = 0; kt < 4; ++kt) {
            v0[kt] = *(const float4*)(xp + kt * 32);
            v1[kt] = *(const float4*)(xp + kt * 32 + 4);
        }
        #pragma unroll
        for (int kt = 0; kt < 4; ++kt) {
            bf16x8 a;
            a[0] = (short)f2bf(v0[kt].x); a[1] = (short)f2bf(v0[kt].y);
            a[2] = (short)f2bf(v0[kt].z); a[3] = (short)f2bf(v0[kt].w);
            a[4] = (short)f2bf(v1[kt].x); a[5] = (short)f2bf(v1[kt].y);
            a[6] = (short)f2bf(v1[kt].z); a[7] = (short)f2bf(v1[kt].w);
            axr[mi][kt] = a;
        }
    }

    // one pass per distinct species in this 16-atom window (1 pass for all
    // but the <=9 bucket-boundary tiles). Wave-uniform loop.
    unsigned rem = 0xFFFFu;
    while (rem) {
        int r0 = __ffs((int)rem) - 1;
        int e  = __shfl(mysp, r0, 64);
        unsigned long long bal = __ballot(mysp == e);
        unsigned mask16 = (unsigned)(bal & 0xFFFFull);
        rem &= ~mask16;

        const unsigned short* wte = wt + (size_t)e * (4 * CC * CC);

        f32x4 acc[4][8];
        #pragma unroll
        for (int i = 0; i < 4; ++i)
            #pragma unroll
            for (int j = 0; j < 8; ++j)
                acc[i][j] = (f32x4){0.f, 0.f, 0.f, 0.f};

        #pragma unroll
        for (int kt = 0; kt < 4; ++kt) {
            bf16x8 bfr[8];
            int lprev = -1;
            #pragma unroll
            for (int mi = 0; mi < 4; ++mi) {
                int l = l_of_m(wv * 4 + mi);
                if (l != lprev) {   // <=2 B-frag group loads per kt per wave
                    #pragma unroll
                    for (int n = 0; n < 8; ++n)
                        bfr[n] = *(const bf16x8*)(wte
                            + ((size_t)(l * CC + n * 16 + l16)) * CC
                            + kt * 32 + quad * 8);
                    lprev = l;
                }
                #pragma unroll
                for (int n = 0; n < 8; ++n)
                    acc[mi][n] = __builtin_amdgcn_mfma_f32_16x16x32_bf16(
                        axr[mi][kt], bfr[n], acc[mi][n], 0, 0, 0);
            }
        }

        // epilogue: C/D layout col = lane&15, row(atom) = quad*4 + reg.
        // scale already folded into wt. Store only rows of species e.
        int  aidr[4]; bool st[4];
        #pragma unroll
        for (int r = 0; r < 4; ++r) {
            int row = quad * 4 + r;
            aidr[r] = __shfl(aid, row, 64);
            st[r]   = (mask16 >> row) & 1u;
        }
        #pragma unroll
        for (int mi = 0; mi < 4; ++mi) {
            #pragma unroll
            for (int n = 0; n < 8; ++n) {
                #pragma unroll
                for (int r = 0; r < 4; ++r) {
                    if (st[r])
                        out[(size_t)aidr[r] * (SHD * CC) + (wv * 4 + mi) * CC
                            + n * 16 + l16] = acc[mi][n][r];
                }
            }
        }
    }
}

extern "C" void kernel_launch(void* const* d_in, const int* in_sizes, int n_in,
                              void* d_out, int out_size, void* d_ws, size_t ws_size,
                              hipStream_t stream) {
    const float* x = (const float*)d_in[0];
    const float* y = (const float*)d_in[1];
    const float* w = (const float*)d_in[2];
    float* out = (float*)d_out;

    // ws: [counts 64B][cursors 64B][offsets 64B][species 200KB][idx 200KB][Wt-bf16 1.31MB]
    char* ws = (char*)d_ws;
    int* counts  = (int*)(ws);
    int* cursors = (int*)(ws + 64);
    int* offsets = (int*)(ws + 128);
    int* species = (int*)(ws + 192);
    int* idxb    = (int*)(ws + 192 + NATOMS * 4);
    unsigned short* wt = (unsigned short*)(ws + 192 + 2 * NATOMS * 4 + 64);

    hipMemsetAsync(d_ws, 0, 192, stream);   // zero counts/cursors/offsets
    k_count  <<<(NATOMS + 255) / 256, 256, 0, stream>>>(y, counts, species);
    k_twt    <<<(NELEM * 4 * CC * CC + 255) / 256, 256, 0, stream>>>(w, wt);
    k_offsets<<<1, 64, 0, stream>>>(counts, offsets);
    k_scatter<<<(NATOMS + 255) / 256, 256, 0, stream>>>(species, offsets, cursors, idxb);
    k_main   <<<NTILES, 256, 0, stream>>>(x, wt, idxb, out);
}